// Round 8
// baseline (218.134 us; speedup 1.0000x reference)
//
#include <hip/hip_runtime.h>
#include <hip/hip_bf16.h>
#include <stdint.h>

// MHA fwd, B=4 T=2048 D=768 H=12 HD=64, fp32 io, NO mask, scale=1/8.
// R13: attn = R11 structure (q64/wave x kt-split, 4 waves, LDS reads halved;
// conflict counter verified 6.29M->3.15M) + amdgpu_waves_per_eu(3,3) to stop
// the compiler's 6-wave/SIMD occupancy heuristic that allocated 84 VGPRs and
// spilled ~15MB/dispatch (R11's +15us confound). 12 waves/CU unchanged.
// prep/qkv/out frozen from R12.

#define HH   12
#define TT   2048
#define DIN  768
#define DOUT 768
#define HD   64
#define BB   4
#define MTOT (BB*TT)      // 8192
#define NQKV (3*DOUT)     // 2304
#define QSCALE 0.1803368801111832f   // 0.125 * log2(e)

typedef float  float4v  __attribute__((ext_vector_type(4)));
typedef float  float16v __attribute__((ext_vector_type(16)));
typedef __bf16 bf16x8   __attribute__((ext_vector_type(8)));
typedef short  short8v  __attribute__((ext_vector_type(8)));

#define AS1 __attribute__((address_space(1)))
#define AS3 __attribute__((address_space(3)))

static __device__ __forceinline__ void gload_lds16(const void* g, void* l) {
    __builtin_amdgcn_global_load_lds((AS1 void*)g, (AS3 void*)l, 16, 0, 0);
}

static __device__ __forceinline__ short f2bf(float f) {
    __bf16 h = (__bf16)f;
    return __builtin_bit_cast(short, h);
}

// ---- Fused prep: z<4 = weight transpose tiles; z==4 = x cast (grid-stride) ----
__global__ __launch_bounds__(256) void prep_kernel(const float* __restrict__ x,
                                                   const float* __restrict__ Wq,
                                                   const float* __restrict__ Wk,
                                                   const float* __restrict__ Wv,
                                                   const float* __restrict__ Wo,
                                                   short* __restrict__ Xb,
                                                   short* __restrict__ Wqkvt,
                                                   short* __restrict__ Wot) {
    __shared__ short tile[32 * 33];
    const int bz = blockIdx.z;
    if (bz == 4) {
        const int n4 = MTOT * DIN / 4;
        int i = (blockIdx.y * 24 + blockIdx.x) * 256 + threadIdx.x;
        for (; i < n4; i += 24 * 24 * 256) {
            float4 v = ((const float4*)x)[i];
            short4 o;
            o.x = f2bf(v.x); o.y = f2bf(v.y); o.z = f2bf(v.z); o.w = f2bf(v.w);
            ((short4*)Xb)[i] = o;
        }
        return;
    }
    const int bx = blockIdx.x, by = blockIdx.y;
    const float* W = (bz == 0) ? Wq : (bz == 1) ? Wk : (bz == 2) ? Wv : Wo;
    const int tx = threadIdx.x & 31, ty = threadIdx.x >> 5;
    for (int i = 0; i < 4; i++) {
        int k = by * 32 + ty + i * 8;
        tile[(ty + i * 8) * 33 + tx] = f2bf(W[(size_t)k * DOUT + bx * 32 + tx]);
    }
    __syncthreads();
    for (int i = 0; i < 4; i++) {
        int n = bx * 32 + ty + i * 8;
        int k = by * 32 + tx;
        short v = tile[tx * 33 + ty + i * 8];
        if (bz < 3) Wqkvt[(size_t)(bz * DOUT + n) * DIN + k] = v;
        else        Wot[(size_t)n * DOUT + k] = v;
    }
}

// ---- QKV GEMM: C[8192][2304] = Xb @ Wqkvt^T, BK=64 (frozen from R8) ----
__global__ __launch_bounds__(256) void qkv_gemm_kernel(const short* __restrict__ Xb,
                                                       const short* __restrict__ Wt,
                                                       short* __restrict__ Qb,
                                                       short* __restrict__ Kb,
                                                       short* __restrict__ Vt) {
    __shared__ __align__(16) short lds[16384];   // GEMM: A|B 32KB; epilogue: 32KB tile
    short* ldsA = lds;           // 128 x 64
    short* ldsB = lds + 8192;    // 128 x 64
    const int t = threadIdx.x;
    const int w = t >> 6, lane = t & 63;
    const int quad = lane >> 4, l15 = lane & 15;
    const int m0 = blockIdx.x * 128, n0 = blockIdx.y * 128;
    const int wm = (w >> 1) * 64, wn = (w & 1) * 64;

    float4v acc[4][4];
    for (int i = 0; i < 4; i++)
        for (int j = 0; j < 4; j++)
            acc[i][j] = (float4v)0.0f;

    const int rA = t >> 3;                               // 0..31
    const int cS = ((t & 7) ^ ((t >> 3) & 7)) * 8;       // source col-granule * 8
    const short* gA0 = Xb + (size_t)(m0 + rA) * DIN + cS;
    const short* gB0 = Wt + (size_t)(n0 + rA) * DIN + cS;

    for (int k0 = 0; k0 < DIN; k0 += 64) {
#pragma unroll
        for (int g = 0; g < 4; g++)
            gload_lds16(gA0 + (size_t)g * 32 * DIN + k0, &ldsA[(g * 256 + t) * 8]);
#pragma unroll
        for (int g = 0; g < 4; g++)
            gload_lds16(gB0 + (size_t)g * 32 * DIN + k0, &ldsB[(g * 256 + t) * 8]);
        __syncthreads();
#pragma unroll
        for (int kk = 0; kk < 2; kk++) {
            bf16x8 af[4], bfr[4];
            const int pos = ((kk * 4 + quad) ^ (l15 & 7)) * 8;
            for (int i = 0; i < 4; i++) af[i]  = *(const bf16x8*)&ldsA[(wm + i * 16 + l15) * 64 + pos];
            for (int j = 0; j < 4; j++) bfr[j] = *(const bf16x8*)&ldsB[(wn + j * 16 + l15) * 64 + pos];
            for (int i = 0; i < 4; i++)
                for (int j = 0; j < 4; j++)
                    acc[i][j] = __builtin_amdgcn_mfma_f32_16x16x32_bf16(af[i], bfr[j], acc[i][j], 0, 0, 0);
        }
        __syncthreads();
    }

    const int which = n0 / DOUT;
    if (which < 2) {
        // Q/K epilogue: single-pass 128x128 LDS tile, 1 barrier, b128 stores.
        short* ldsT = lds;   // 128 x 128 shorts = 32 KB
        const float sc = (which == 0) ? QSCALE : 1.0f;
        short* dst = (which == 0) ? Qb : Kb;
        const int n0sec = n0 - which * DOUT;
        for (int i = 0; i < 4; i++)
            for (int j = 0; j < 4; j++) {
                int col = wn + j * 16 + l15;
                int cx = col >> 3, co = col & 7;
                for (int r = 0; r < 4; r++) {
                    int row = wm + i * 16 + quad * 4 + r;
                    ldsT[row * 128 + ((cx ^ (row & 7)) * 8 + co)] = f2bf(acc[i][j][r] * sc);
                }
            }
        __syncthreads();
        for (int p = 0; p < 8; p++) {
            int row = p * 16 + (t >> 4);
            int cL = t & 15;
            short8v v = *(const short8v*)&ldsT[row * 128 + ((cL ^ (row & 7)) * 8)];
            int mg = m0 + row;
            int b2 = mg >> 11, tq = mg & 2047;
            int colg = n0sec + cL * 8;
            int hh = colg >> 6, d = colg & 63;
            *(short8v*)&dst[((size_t)((b2 * HH + hh) * TT + tq) << 6) + d] = v;
        }
    } else {
        // V epilogue: single-pass transpose 128(d) x 128(t) LDS tile, b128 stores.
        short* ldsT = lds;   // 128 x 128 shorts = 32 KB
        const int n0r = n0 - 2 * DOUT;
        const int b = m0 >> 11, tq0 = m0 & 2047;
        for (int i = 0; i < 4; i++)
            for (int j = 0; j < 4; j++)
                for (int r = 0; r < 4; r++) {
                    int nl = wn + j * 16 + l15;            // d-direction 0..127
                    int ml = wm + i * 16 + quad * 4 + r;   // t-direction 0..127
                    int c = ml >> 3, o = ml & 7;
                    ldsT[nl * 128 + ((c ^ (nl & 7)) * 8 + o)] = f2bf(acc[i][j][r]);
                }
        __syncthreads();
        for (int p = 0; p < 8; p++) {
            int nrow = p * 16 + (t >> 4);
            int cc = t & 15;
            short8v v = *(const short8v*)&ldsT[nrow * 128 + ((cc ^ (nrow & 7)) * 8)];
            int colg = n0r + nrow;
            int hh = colg >> 6, d = colg & 63;
            *(short8v*)&Vt[(size_t)((b * HH + hh) * HD + d) * TT + tq0 + cc * 8] = v;
        }
    }
}

// ---- Flash attention R13: R11 structure (4 waves = qg x kt, q64/wave,
// halved LDS reads) + waves_per_eu(3,3) to prevent the spill-inducing
// 6-wave/SIMD allocation heuristic. kt partials combined via LDS dump. ----
__global__ __launch_bounds__(256)
__attribute__((amdgpu_waves_per_eu(3, 3)))
void attn_kernel(const short* __restrict__ Qb,
                 const short* __restrict__ Kb,
                 const short* __restrict__ Vt,
                 short* __restrict__ Ctx) {
    __shared__ __align__(16) short ldsK[2][64 * 64];   // 16 KB (combine: qg0 dump)
    __shared__ __align__(16) short ldsV[2][64 * 64];   // 16 KB (combine: qg1 dump)
    __shared__ float lsb[256];                         // 1 KB
    const int t = threadIdx.x;
    const int w = t >> 6, lane = t & 63;
    const int half = lane >> 5, m = lane & 31;
    const int qg = w & 1, kt = w >> 1;
    const int bh = blockIdx.x;
    const int b = bh / HH, h = bh - b * HH;
    const int q0 = blockIdx.y * 128 + qg * 64;   // wave owns 64 q-rows

    const short* Qbase = Qb + (size_t)bh * TT * HD;
    const short* Kbase = Kb + (size_t)bh * TT * HD;
    const short* Vbase = Vt + (size_t)bh * HD * TT;

    bf16x8 qf[2][4];
#pragma unroll
    for (int qh = 0; qh < 2; qh++)
#pragma unroll
        for (int s = 0; s < 4; s++)
            qf[qh][s] = *(const bf16x8*)&Qbase[(q0 + qh * 32 + m) * HD + s * 16 + half * 8];

    // Staging identical to R5/R8 (256 threads, 2 K + 2 V granules each).
    int kOff[2], vOff[2];
    {
        int r5 = t >> 3;
        int pi = ((r5 >> 3) & 1) * 16 + ((r5 >> 2) & 1) * 8 + ((r5 >> 4) & 1) * 4 + (r5 & 3);
#pragma unroll
        for (int g = 0; g < 2; g++) {
            kOff[g] = (g * 32 + pi) * 64 + (((t & 7) ^ (r5 & 7)) * 8);
            int vrow = g * 32 + r5;
            vOff[g] = vrow * TT + (((t & 7) ^ (vrow & 7)) * 8);
        }
    }

    auto stage = [&](int buf, int u0) {
#pragma unroll
        for (int g = 0; g < 2; g++)
            gload_lds16(Kbase + (size_t)u0 * 64 + kOff[g], &ldsK[buf][(g * 256 + t) * 8]);
#pragma unroll
        for (int g = 0; g < 2; g++)
            gload_lds16(Vbase + (size_t)u0 + vOff[g], &ldsV[buf][(g * 256 + t) * 8]);
    };

    float16v accO[2][2];   // [qh][dt]
#pragma unroll
    for (int qh = 0; qh < 2; qh++)
#pragma unroll
        for (int dt = 0; dt < 2; dt++)
            accO[qh][dt] = (float16v)0.0f;
    float lsum[2] = {0.0f, 0.0f};

    stage(0, 0);

    for (int it = 0; it < TT / 64; ++it) {
        __syncthreads();
        const int buf = it & 1;
        if (it + 1 < TT / 64) stage(buf ^ 1, (it + 1) * 64);
        const short* K_ = &ldsK[buf][0];
        const short* V_ = &ldsV[buf][0];

        // QK for this wave's kt half, both q-halves share each ka read.
        float16v st0 = (float16v)0.0f;
        float16v st1 = (float16v)0.0f;
        __builtin_amdgcn_s_setprio(1);
#pragma unroll
        for (int s = 0; s < 4; s++) {
            bf16x8 ka = *(const bf16x8*)&K_[(kt * 32 + m) * 64 + (((s * 2 + half) ^ (m & 7)) * 8)];
            st0 = __builtin_amdgcn_mfma_f32_32x32x16_bf16(ka, qf[0][s], st0, 0, 0, 0);
            st1 = __builtin_amdgcn_mfma_f32_32x32x16_bf16(ka, qf[1][s], st1, 0, 0, 0);
        }
        __builtin_amdgcn_s_setprio(0);

        bf16x8 ap[2][2];
#pragma unroll
        for (int qh = 0; qh < 2; qh++) {
            float pe[16];
#pragma unroll
            for (int i = 0; i < 16; i++)
                pe[i] = __builtin_amdgcn_exp2f(qh ? st1[i] : st0[i]);
#pragma unroll
            for (int i = 0; i < 4; i++) {
                ap[qh][0][i]     = (__bf16)pe[i];
                ap[qh][0][4 + i] = (__bf16)pe[8 + i];
                ap[qh][1][i]     = (__bf16)pe[4 + i];
                ap[qh][1][4 + i] = (__bf16)pe[12 + i];
            }
            float ps[8];
#pragma unroll
            for (int i = 0; i < 8; i++) ps[i] = pe[i] + pe[i + 8];
#pragma unroll
            for (int i = 0; i < 4; i++) ps[i] += ps[i + 4];
            ps[0] += ps[2]; ps[1] += ps[3];
            lsum[qh] += ps[0] + ps[1];
        }

        // PV: each bv read feeds both q-halves.
        __builtin_amdgcn_s_setprio(1);
#pragma unroll
        for (int ks = 0; ks < 2; ks++)
#pragma unroll
            for (int dt = 0; dt < 2; dt++) {
                int row = dt * 32 + m;
                bf16x8 bv = *(const bf16x8*)&V_[row * 64 + (((kt * 4 + ks * 2 + half) ^ (row & 7)) * 8)];
                accO[0][dt] = __builtin_amdgcn_mfma_f32_32x32x16_bf16(ap[0][ks], bv, accO[0][dt], 0, 0, 0);
                accO[1][dt] = __builtin_amdgcn_mfma_f32_32x32x16_bf16(ap[1][ks], bv, accO[1][dt], 0, 0, 0);
            }
        __builtin_amdgcn_s_setprio(0);
    }

    // ---- Combine kt=1 partials into kt=0 waves (one-time, 16KB per pair) ----
    __syncthreads();
    float* dump = (qg == 0) ? (float*)&ldsK[0][0] : (float*)&ldsV[0][0];  // 4096 floats
    if (kt == 1) {
#pragma unroll
        for (int qh = 0; qh < 2; qh++) {
#pragma unroll
            for (int dt = 0; dt < 2; dt++)
#pragma unroll
                for (int r = 0; r < 16; r++)
                    dump[((qh * 2 + dt) * 16 + r) * 64 + lane] = accO[qh][dt][r];
            lsb[(qg * 2 + qh) * 64 + lane] = lsum[qh];
        }
    }
    __syncthreads();
    if (kt == 0) {
#pragma unroll
        for (int qh = 0; qh < 2; qh++) {
#pragma unroll
            for (int dt = 0; dt < 2; dt++)
#pragma unroll
                for (int r = 0; r < 16; r++)
                    accO[qh][dt][r] += dump[((qh * 2 + dt) * 16 + r) * 64 + lane];
            lsum[qh] += lsb[(qg * 2 + qh) * 64 + lane];
        }
#pragma unroll
        for (int qh = 0; qh < 2; qh++) {
            float v = lsum[qh] + __shfl_xor(lsum[qh], 32);
            float linv = 1.0f / v;
#pragma unroll
            for (int s = 0; s < 4; s++)
#pragma unroll
                for (int i = 0; i < 4; i++) {
                    int reg = s * 4 + i;
                    int qrow = i + s * 8 + half * 4;
                    float ln = __shfl(linv, qrow);
                    int qg2 = q0 + qh * 32 + qrow;
                    size_t base = (size_t)(b * TT + qg2) * DOUT + h * HD + m;
                    Ctx[base]      = f2bf(accO[qh][0][reg] * ln);
                    Ctx[base + 32] = f2bf(accO[qh][1][reg] * ln);
                }
        }
    }
}

// ---- Out GEMM R12: 64x128 tiles, BK=64, grid 128x6 = 768 blocks = 3/CU ----
__global__ __launch_bounds__(256) void out_gemm_kernel(const short* __restrict__ Cb,
                                                       const short* __restrict__ Wot,
                                                       const float* __restrict__ bo,
                                                       float* __restrict__ out) {
    __shared__ __align__(16) short ldsA[64 * 64];    //  8 KB
    __shared__ __align__(16) short ldsB[128 * 64];   // 16 KB
    const int t = threadIdx.x;
    const int w = t >> 6, lane = t & 63;
    const int quad = lane >> 4, l15 = lane & 15;
    const int m0 = blockIdx.x * 64, n0 = blockIdx.y * 128;
    const int wn = w * 32;

    float4v acc[4][2];
    for (int i = 0; i < 4; i++)
        for (int j = 0; j < 2; j++)
            acc[i][j] = (float4v)0.0f;

    const int rA = t >> 3;                               // 0..31
    const int cS = ((t & 7) ^ ((t >> 3) & 7)) * 8;       // source col-granule * 8
    const short* gA0 = Cb + (size_t)(m0 + rA) * DOUT + cS;
    const short* gB0 = Wot + (size_t)(n0 + rA) * DOUT + cS;

    for (int k0 = 0; k0 < DOUT; k0 += 64) {
#pragma unroll
        for (int g = 0; g < 2; g++)
            gload_lds16(gA0 + (size_t)g * 32 * DOUT + k0, &ldsA[(g * 256 + t) * 8]);
#pragma unroll
        for (int g = 0; g < 4; g++)
            gload_lds16(gB0 + (size_t)g * 32 * DOUT + k0, &ldsB[(g * 256 + t) * 8]);
        __syncthreads();
#pragma unroll
        for (int kk = 0; kk < 2; kk++) {
            bf16x8 af[4], bfr[2];
            const int pos = ((kk * 4 + quad) ^ (l15 & 7)) * 8;
            for (int i = 0; i < 4; i++) af[i]  = *(const bf16x8*)&ldsA[(i * 16 + l15) * 64 + pos];
            for (int j = 0; j < 2; j++) bfr[j] = *(const bf16x8*)&ldsB[(wn + j * 16 + l15) * 64 + pos];
            for (int i = 0; i < 4; i++)
                for (int j = 0; j < 2; j++)
                    acc[i][j] = __builtin_amdgcn_mfma_f32_16x16x32_bf16(af[i], bfr[j], acc[i][j], 0, 0, 0);
        }
        __syncthreads();
    }

    for (int i = 0; i < 4; i++) {
        int m = m0 + i * 16 + quad * 4;
        for (int j = 0; j < 2; j++) {
            int n = n0 + wn + j * 16 + l15;
            float bias = bo[n];
            for (int r = 0; r < 4; r++)
                out[(size_t)(m + r) * DOUT + n] = acc[i][j][r] + bias;
        }
    }
}

extern "C" void kernel_launch(void* const* d_in, const int* in_sizes, int n_in,
                              void* d_out, int out_size, void* d_ws, size_t ws_size,
                              hipStream_t stream) {
    const float* x  = (const float*)d_in[0];
    const float* Wq = (const float*)d_in[1];
    const float* Wk = (const float*)d_in[2];
    const float* Wv = (const float*)d_in[3];
    const float* Wo = (const float*)d_in[4];
    const float* bo = (const float*)d_in[5];
    float* out = (float*)d_out;

    char* ws = (char*)d_ws;
    short* Xb    = (short*)(ws + 0);          // 12582912
    short* Wqkvt = (short*)(ws + 12582912);   //  3538944
    short* Wot   = (short*)(ws + 16121856);   //  1179648
    short* Qb    = (short*)(ws + 17301504);   // 12582912
    short* Kb    = (short*)(ws + 29884416);   // 12582912
    short* Vt    = (short*)(ws + 42467328);   // 12582912
    short* Cb    = (short*)(ws + 55050240);   // 12582912 -> total 67633152 B

    prep_kernel<<<dim3(24, 24, 5), 256, 0, stream>>>(x, Wq, Wk, Wv, Wo, Xb, Wqkvt, Wot);
    qkv_gemm_kernel<<<dim3(MTOT / 128, NQKV / 128), 256, 0, stream>>>(Xb, Wqkvt, Qb, Kb, Vt);
    attn_kernel<<<dim3(BB * HH, TT / 128), 256, 0, stream>>>(Qb, Kb, Vt, Cb);
    out_gemm_kernel<<<dim3(MTOT / 64, DOUT / 128), 256, 0, stream>>>(Cb, Wot, bo, out);
}

// Round 9
// 216.144 us; speedup vs baseline: 1.0092x; 1.0092x over previous
//
#include <hip/hip_runtime.h>
#include <hip/hip_bf16.h>
#include <stdint.h>

// MHA fwd, B=4 T=2048 D=768 H=12 HD=64, fp32 io, NO mask, scale=1/8.
// R14 (DIAGNOSTIC): R12-exact, but attn launched as TWO y-half dispatches so
// the top-5 profile reveals qkv_gemm/out_gemm durations (never measured --
// attn iterations flooded all 5 slots). Accepted ~15-25us attn occupancy
// penalty this round; R12's 204.3 stays the banked best. attn math identical.

#define HH   12
#define TT   2048
#define DIN  768
#define DOUT 768
#define HD   64
#define BB   4
#define MTOT (BB*TT)      // 8192
#define NQKV (3*DOUT)     // 2304
#define QSCALE 0.1803368801111832f   // 0.125 * log2(e)

typedef float  float4v  __attribute__((ext_vector_type(4)));
typedef float  float16v __attribute__((ext_vector_type(16)));
typedef __bf16 bf16x8   __attribute__((ext_vector_type(8)));
typedef short  short8v  __attribute__((ext_vector_type(8)));

#define AS1 __attribute__((address_space(1)))
#define AS3 __attribute__((address_space(3)))

static __device__ __forceinline__ void gload_lds16(const void* g, void* l) {
    __builtin_amdgcn_global_load_lds((AS1 void*)g, (AS3 void*)l, 16, 0, 0);
}

static __device__ __forceinline__ short f2bf(float f) {
    __bf16 h = (__bf16)f;
    return __builtin_bit_cast(short, h);
}

// ---- Fused prep: z<4 = weight transpose tiles; z==4 = x cast (grid-stride) ----
__global__ __launch_bounds__(256) void prep_kernel(const float* __restrict__ x,
                                                   const float* __restrict__ Wq,
                                                   const float* __restrict__ Wk,
                                                   const float* __restrict__ Wv,
                                                   const float* __restrict__ Wo,
                                                   short* __restrict__ Xb,
                                                   short* __restrict__ Wqkvt,
                                                   short* __restrict__ Wot) {
    __shared__ short tile[32 * 33];
    const int bz = blockIdx.z;
    if (bz == 4) {
        const int n4 = MTOT * DIN / 4;
        int i = (blockIdx.y * 24 + blockIdx.x) * 256 + threadIdx.x;
        for (; i < n4; i += 24 * 24 * 256) {
            float4 v = ((const float4*)x)[i];
            short4 o;
            o.x = f2bf(v.x); o.y = f2bf(v.y); o.z = f2bf(v.z); o.w = f2bf(v.w);
            ((short4*)Xb)[i] = o;
        }
        return;
    }
    const int bx = blockIdx.x, by = blockIdx.y;
    const float* W = (bz == 0) ? Wq : (bz == 1) ? Wk : (bz == 2) ? Wv : Wo;
    const int tx = threadIdx.x & 31, ty = threadIdx.x >> 5;
    for (int i = 0; i < 4; i++) {
        int k = by * 32 + ty + i * 8;
        tile[(ty + i * 8) * 33 + tx] = f2bf(W[(size_t)k * DOUT + bx * 32 + tx]);
    }
    __syncthreads();
    for (int i = 0; i < 4; i++) {
        int n = bx * 32 + ty + i * 8;
        int k = by * 32 + tx;
        short v = tile[tx * 33 + ty + i * 8];
        if (bz < 3) Wqkvt[(size_t)(bz * DOUT + n) * DIN + k] = v;
        else        Wot[(size_t)n * DOUT + k] = v;
    }
}

// ---- QKV GEMM: C[8192][2304] = Xb @ Wqkvt^T, BK=64 (frozen from R8) ----
__global__ __launch_bounds__(256) void qkv_gemm_kernel(const short* __restrict__ Xb,
                                                       const short* __restrict__ Wt,
                                                       short* __restrict__ Qb,
                                                       short* __restrict__ Kb,
                                                       short* __restrict__ Vt) {
    __shared__ __align__(16) short lds[16384];   // GEMM: A|B 32KB; epilogue: 32KB tile
    short* ldsA = lds;           // 128 x 64
    short* ldsB = lds + 8192;    // 128 x 64
    const int t = threadIdx.x;
    const int w = t >> 6, lane = t & 63;
    const int quad = lane >> 4, l15 = lane & 15;
    const int m0 = blockIdx.x * 128, n0 = blockIdx.y * 128;
    const int wm = (w >> 1) * 64, wn = (w & 1) * 64;

    float4v acc[4][4];
    for (int i = 0; i < 4; i++)
        for (int j = 0; j < 4; j++)
            acc[i][j] = (float4v)0.0f;

    const int rA = t >> 3;                               // 0..31
    const int cS = ((t & 7) ^ ((t >> 3) & 7)) * 8;       // source col-granule * 8
    const short* gA0 = Xb + (size_t)(m0 + rA) * DIN + cS;
    const short* gB0 = Wt + (size_t)(n0 + rA) * DIN + cS;

    for (int k0 = 0; k0 < DIN; k0 += 64) {
#pragma unroll
        for (int g = 0; g < 4; g++)
            gload_lds16(gA0 + (size_t)g * 32 * DIN + k0, &ldsA[(g * 256 + t) * 8]);
#pragma unroll
        for (int g = 0; g < 4; g++)
            gload_lds16(gB0 + (size_t)g * 32 * DIN + k0, &ldsB[(g * 256 + t) * 8]);
        __syncthreads();
#pragma unroll
        for (int kk = 0; kk < 2; kk++) {
            bf16x8 af[4], bfr[4];
            const int pos = ((kk * 4 + quad) ^ (l15 & 7)) * 8;
            for (int i = 0; i < 4; i++) af[i]  = *(const bf16x8*)&ldsA[(wm + i * 16 + l15) * 64 + pos];
            for (int j = 0; j < 4; j++) bfr[j] = *(const bf16x8*)&ldsB[(wn + j * 16 + l15) * 64 + pos];
            for (int i = 0; i < 4; i++)
                for (int j = 0; j < 4; j++)
                    acc[i][j] = __builtin_amdgcn_mfma_f32_16x16x32_bf16(af[i], bfr[j], acc[i][j], 0, 0, 0);
        }
        __syncthreads();
    }

    const int which = n0 / DOUT;
    if (which < 2) {
        // Q/K epilogue: single-pass 128x128 LDS tile, 1 barrier, b128 stores.
        short* ldsT = lds;   // 128 x 128 shorts = 32 KB
        const float sc = (which == 0) ? QSCALE : 1.0f;
        short* dst = (which == 0) ? Qb : Kb;
        const int n0sec = n0 - which * DOUT;
        for (int i = 0; i < 4; i++)
            for (int j = 0; j < 4; j++) {
                int col = wn + j * 16 + l15;
                int cx = col >> 3, co = col & 7;
                for (int r = 0; r < 4; r++) {
                    int row = wm + i * 16 + quad * 4 + r;
                    ldsT[row * 128 + ((cx ^ (row & 7)) * 8 + co)] = f2bf(acc[i][j][r] * sc);
                }
            }
        __syncthreads();
        for (int p = 0; p < 8; p++) {
            int row = p * 16 + (t >> 4);
            int cL = t & 15;
            short8v v = *(const short8v*)&ldsT[row * 128 + ((cL ^ (row & 7)) * 8)];
            int mg = m0 + row;
            int b2 = mg >> 11, tq = mg & 2047;
            int colg = n0sec + cL * 8;
            int hh = colg >> 6, d = colg & 63;
            *(short8v*)&dst[((size_t)((b2 * HH + hh) * TT + tq) << 6) + d] = v;
        }
    } else {
        // V epilogue: single-pass transpose 128(d) x 128(t) LDS tile, b128 stores.
        short* ldsT = lds;   // 128 x 128 shorts = 32 KB
        const int n0r = n0 - 2 * DOUT;
        const int b = m0 >> 11, tq0 = m0 & 2047;
        for (int i = 0; i < 4; i++)
            for (int j = 0; j < 4; j++)
                for (int r = 0; r < 4; r++) {
                    int nl = wn + j * 16 + l15;            // d-direction 0..127
                    int ml = wm + i * 16 + quad * 4 + r;   // t-direction 0..127
                    int c = ml >> 3, o = ml & 7;
                    ldsT[nl * 128 + ((c ^ (nl & 7)) * 8 + o)] = f2bf(acc[i][j][r]);
                }
        __syncthreads();
        for (int p = 0; p < 8; p++) {
            int nrow = p * 16 + (t >> 4);
            int cc = t & 15;
            short8v v = *(const short8v*)&ldsT[nrow * 128 + ((cc ^ (nrow & 7)) * 8)];
            int colg = n0r + nrow;
            int hh = colg >> 6, d = colg & 63;
            *(short8v*)&Vt[(size_t)((b * HH + hh) * HD + d) * TT + tq0 + cc * 8] = v;
        }
    }
}

// ---- Flash attention (R12/R9 math, y-offset param for split launch) ----
__global__ __launch_bounds__(256, 3) void attn_kernel(const short* __restrict__ Qb,
                                                      const short* __restrict__ Kb,
                                                      const short* __restrict__ Vt,
                                                      short* __restrict__ Ctx,
                                                      int y0) {
    __shared__ __align__(16) short ldsK[2][64 * 64];
    __shared__ __align__(16) short ldsV[2][64 * 64];
    const int t = threadIdx.x;
    const int w = t >> 6, lane = t & 63;
    const int half = lane >> 5, m = lane & 31;
    const int bh = blockIdx.x;
    const int b = bh / HH, h = bh - b * HH;
    const int q0 = (y0 + blockIdx.y) * 128 + w * 32;

    const short* Qbase = Qb + (size_t)bh * TT * HD;
    const short* Kbase = Kb + (size_t)bh * TT * HD;
    const short* Vbase = Vt + (size_t)bh * HD * TT;

    bf16x8 qf[4];
#pragma unroll
    for (int s = 0; s < 4; s++)
        qf[s] = *(const bf16x8*)&Qbase[(q0 + m) * HD + s * 16 + half * 8];

    int kOff[2], vOff[2];
    {
        int r5 = t >> 3;
        int pi = ((r5 >> 3) & 1) * 16 + ((r5 >> 2) & 1) * 8 + ((r5 >> 4) & 1) * 4 + (r5 & 3);
#pragma unroll
        for (int g = 0; g < 2; g++) {
            kOff[g] = (g * 32 + pi) * 64 + (((t & 7) ^ (r5 & 7)) * 8);
            int vrow = g * 32 + r5;
            vOff[g] = vrow * TT + (((t & 7) ^ (vrow & 7)) * 8);
        }
    }

    auto stage = [&](int buf, int u0) {
#pragma unroll
        for (int g = 0; g < 2; g++)
            gload_lds16(Kbase + (size_t)u0 * 64 + kOff[g], &ldsK[buf][(g * 256 + t) * 8]);
#pragma unroll
        for (int g = 0; g < 2; g++)
            gload_lds16(Vbase + (size_t)u0 + vOff[g], &ldsV[buf][(g * 256 + t) * 8]);
    };

    float16v accO[2];
    accO[0] = (float16v)0.0f;
    accO[1] = (float16v)0.0f;
    float lsum = 0.0f;

    stage(0, 0);

    for (int it = 0; it < TT / 64; ++it) {
        __syncthreads();
        const int buf = it & 1;
        if (it + 1 < TT / 64) stage(buf ^ 1, (it + 1) * 64);
        const short* K_ = &ldsK[buf][0];
        const short* V_ = &ldsV[buf][0];

        // ---- QK for both kt halves: two independent accumulation chains ----
        float16v st0 = (float16v)0.0f;
        float16v st1 = (float16v)0.0f;
        __builtin_amdgcn_s_setprio(1);
#pragma unroll
        for (int s = 0; s < 4; s++) {
            bf16x8 ka = *(const bf16x8*)&K_[m * 64 + (((s * 2 + half) ^ (m & 7)) * 8)];
            st0 = __builtin_amdgcn_mfma_f32_32x32x16_bf16(ka, qf[s], st0, 0, 0, 0);
        }
#pragma unroll
        for (int s = 0; s < 4; s++) {
            bf16x8 ka = *(const bf16x8*)&K_[(32 + m) * 64 + (((s * 2 + half) ^ (m & 7)) * 8)];
            st1 = __builtin_amdgcn_mfma_f32_32x32x16_bf16(ka, qf[s], st1, 0, 0, 0);
        }
        __builtin_amdgcn_s_setprio(0);

        // ---- kt=0: softmax (overlaps QK1 in-flight), PV, then tree-sum ----
        {
            float pe[16];
#pragma unroll
            for (int i = 0; i < 16; i++) pe[i] = __builtin_amdgcn_exp2f(st0[i]);
            bf16x8 ap[2];
#pragma unroll
            for (int i = 0; i < 4; i++) {
                ap[0][i]     = (__bf16)pe[i];
                ap[0][4 + i] = (__bf16)pe[8 + i];
                ap[1][i]     = (__bf16)pe[4 + i];
                ap[1][4 + i] = (__bf16)pe[12 + i];
            }
            __builtin_amdgcn_s_setprio(1);
#pragma unroll
            for (int ks = 0; ks < 2; ks++)
#pragma unroll
                for (int dt = 0; dt < 2; dt++) {
                    int row = dt * 32 + m;
                    bf16x8 bv = *(const bf16x8*)&V_[row * 64 + (((ks * 2 + half) ^ (row & 7)) * 8)];
                    accO[dt] = __builtin_amdgcn_mfma_f32_32x32x16_bf16(ap[ks], bv, accO[dt], 0, 0, 0);
                }
            __builtin_amdgcn_s_setprio(0);
            float ps[8];
#pragma unroll
            for (int i = 0; i < 8; i++) ps[i] = pe[i] + pe[i + 8];
#pragma unroll
            for (int i = 0; i < 4; i++) ps[i] += ps[i + 4];
            ps[0] += ps[2]; ps[1] += ps[3];
            lsum += ps[0] + ps[1];
        }

        // ---- kt=1: softmax (overlaps PV0 in-flight), PV, tree-sum ----
        {
            float pe[16];
#pragma unroll
            for (int i = 0; i < 16; i++) pe[i] = __builtin_amdgcn_exp2f(st1[i]);
            bf16x8 ap[2];
#pragma unroll
            for (int i = 0; i < 4; i++) {
                ap[0][i]     = (__bf16)pe[i];
                ap[0][4 + i] = (__bf16)pe[8 + i];
                ap[1][i]     = (__bf16)pe[4 + i];
                ap[1][4 + i] = (__bf16)pe[12 + i];
            }
            __builtin_amdgcn_s_setprio(1);
#pragma unroll
            for (int ks = 0; ks < 2; ks++)
#pragma unroll
                for (int dt = 0; dt < 2; dt++) {
                    int row = dt * 32 + m;
                    bf16x8 bv = *(const bf16x8*)&V_[row * 64 + (((4 + ks * 2 + half) ^ (row & 7)) * 8)];
                    accO[dt] = __builtin_amdgcn_mfma_f32_32x32x16_bf16(ap[ks], bv, accO[dt], 0, 0, 0);
                }
            __builtin_amdgcn_s_setprio(0);
            float ps[8];
#pragma unroll
            for (int i = 0; i < 8; i++) ps[i] = pe[i] + pe[i + 8];
#pragma unroll
            for (int i = 0; i < 4; i++) ps[i] += ps[i + 4];
            ps[0] += ps[2]; ps[1] += ps[3];
            lsum += ps[0] + ps[1];
        }
    }

    {
        float v = lsum + __shfl_xor(lsum, 32);
        float linv = 1.0f / v;
#pragma unroll
        for (int s = 0; s < 4; s++)
#pragma unroll
            for (int i = 0; i < 4; i++) {
                int reg = s * 4 + i;
                int qrow = i + s * 8 + half * 4;
                float ln = __shfl(linv, qrow);
                int qg = q0 + qrow;
                size_t base = (size_t)(b * TT + qg) * DOUT + h * HD + m;
                Ctx[base]      = f2bf(accO[0][reg] * ln);
                Ctx[base + 32] = f2bf(accO[1][reg] * ln);
            }
    }
}

// ---- Out GEMM R12: 64x128 tiles, BK=64, grid 128x6 = 768 blocks = 3/CU ----
__global__ __launch_bounds__(256) void out_gemm_kernel(const short* __restrict__ Cb,
                                                       const short* __restrict__ Wot,
                                                       const float* __restrict__ bo,
                                                       float* __restrict__ out) {
    __shared__ __align__(16) short ldsA[64 * 64];    //  8 KB
    __shared__ __align__(16) short ldsB[128 * 64];   // 16 KB
    const int t = threadIdx.x;
    const int w = t >> 6, lane = t & 63;
    const int quad = lane >> 4, l15 = lane & 15;
    const int m0 = blockIdx.x * 64, n0 = blockIdx.y * 128;
    const int wn = w * 32;

    float4v acc[4][2];
    for (int i = 0; i < 4; i++)
        for (int j = 0; j < 2; j++)
            acc[i][j] = (float4v)0.0f;

    const int rA = t >> 3;                               // 0..31
    const int cS = ((t & 7) ^ ((t >> 3) & 7)) * 8;       // source col-granule * 8
    const short* gA0 = Cb + (size_t)(m0 + rA) * DOUT + cS;
    const short* gB0 = Wot + (size_t)(n0 + rA) * DOUT + cS;

    for (int k0 = 0; k0 < DOUT; k0 += 64) {
#pragma unroll
        for (int g = 0; g < 2; g++)
            gload_lds16(gA0 + (size_t)g * 32 * DOUT + k0, &ldsA[(g * 256 + t) * 8]);
#pragma unroll
        for (int g = 0; g < 4; g++)
            gload_lds16(gB0 + (size_t)g * 32 * DOUT + k0, &ldsB[(g * 256 + t) * 8]);
        __syncthreads();
#pragma unroll
        for (int kk = 0; kk < 2; kk++) {
            bf16x8 af[4], bfr[2];
            const int pos = ((kk * 4 + quad) ^ (l15 & 7)) * 8;
            for (int i = 0; i < 4; i++) af[i]  = *(const bf16x8*)&ldsA[(i * 16 + l15) * 64 + pos];
            for (int j = 0; j < 2; j++) bfr[j] = *(const bf16x8*)&ldsB[(wn + j * 16 + l15) * 64 + pos];
            for (int i = 0; i < 4; i++)
                for (int j = 0; j < 2; j++)
                    acc[i][j] = __builtin_amdgcn_mfma_f32_16x16x32_bf16(af[i], bfr[j], acc[i][j], 0, 0, 0);
        }
        __syncthreads();
    }

    for (int i = 0; i < 4; i++) {
        int m = m0 + i * 16 + quad * 4;
        for (int j = 0; j < 2; j++) {
            int n = n0 + wn + j * 16 + l15;
            float bias = bo[n];
            for (int r = 0; r < 4; r++)
                out[(size_t)(m + r) * DOUT + n] = acc[i][j][r] + bias;
        }
    }
}

extern "C" void kernel_launch(void* const* d_in, const int* in_sizes, int n_in,
                              void* d_out, int out_size, void* d_ws, size_t ws_size,
                              hipStream_t stream) {
    const float* x  = (const float*)d_in[0];
    const float* Wq = (const float*)d_in[1];
    const float* Wk = (const float*)d_in[2];
    const float* Wv = (const float*)d_in[3];
    const float* Wo = (const float*)d_in[4];
    const float* bo = (const float*)d_in[5];
    float* out = (float*)d_out;

    char* ws = (char*)d_ws;
    short* Xb    = (short*)(ws + 0);          // 12582912
    short* Wqkvt = (short*)(ws + 12582912);   //  3538944
    short* Wot   = (short*)(ws + 16121856);   //  1179648
    short* Qb    = (short*)(ws + 17301504);   // 12582912
    short* Kb    = (short*)(ws + 29884416);   // 12582912
    short* Vt    = (short*)(ws + 42467328);   // 12582912
    short* Cb    = (short*)(ws + 55050240);   // 12582912 -> total 67633152 B

    prep_kernel<<<dim3(24, 24, 5), 256, 0, stream>>>(x, Wq, Wk, Wv, Wo, Xb, Wqkvt, Wot);
    qkv_gemm_kernel<<<dim3(MTOT / 128, NQKV / 128), 256, 0, stream>>>(Xb, Wqkvt, Qb, Kb, Vt);
    attn_kernel<<<dim3(BB * HH, 8), 256, 0, stream>>>(Qb, Kb, Vt, Cb, 0);
    attn_kernel<<<dim3(BB * HH, 8), 256, 0, stream>>>(Qb, Kb, Vt, Cb, 8);
    out_gemm_kernel<<<dim3(MTOT / 64, DOUT / 128), 256, 0, stream>>>(Cb, Wot, bo, out);
}

// Round 10
// 207.432 us; speedup vs baseline: 1.0516x; 1.0420x over previous
//
#include <hip/hip_runtime.h>
#include <hip/hip_bf16.h>
#include <stdint.h>

// MHA fwd, B=4 T=2048 D=768 H=12 HD=64, fp32 io, NO mask, scale=1/8.
// R15: qkv_gemm + out_gemm converted to attn-style prefetch double-buffer
// (BK=32, 2 buffer sets, same LDS footprint, 1 barrier/iter). R14 diagnostic
// showed qkv at 49.7us with MfmaUtil 22 / VALU 19 / HBM 17.5 -- pure exposed
// latency: old loop staged-then-drained with zero overlap. attn restored to
// R12 single dispatch (60.5us banked). prep frozen.

#define HH   12
#define TT   2048
#define DIN  768
#define DOUT 768
#define HD   64
#define BB   4
#define MTOT (BB*TT)      // 8192
#define NQKV (3*DOUT)     // 2304
#define QSCALE 0.1803368801111832f   // 0.125 * log2(e)

typedef float  float4v  __attribute__((ext_vector_type(4)));
typedef float  float16v __attribute__((ext_vector_type(16)));
typedef __bf16 bf16x8   __attribute__((ext_vector_type(8)));
typedef short  short8v  __attribute__((ext_vector_type(8)));

#define AS1 __attribute__((address_space(1)))
#define AS3 __attribute__((address_space(3)))

static __device__ __forceinline__ void gload_lds16(const void* g, void* l) {
    __builtin_amdgcn_global_load_lds((AS1 void*)g, (AS3 void*)l, 16, 0, 0);
}

static __device__ __forceinline__ short f2bf(float f) {
    __bf16 h = (__bf16)f;
    return __builtin_bit_cast(short, h);
}

// ---- Fused prep: z<4 = weight transpose tiles; z==4 = x cast (grid-stride) ----
__global__ __launch_bounds__(256) void prep_kernel(const float* __restrict__ x,
                                                   const float* __restrict__ Wq,
                                                   const float* __restrict__ Wk,
                                                   const float* __restrict__ Wv,
                                                   const float* __restrict__ Wo,
                                                   short* __restrict__ Xb,
                                                   short* __restrict__ Wqkvt,
                                                   short* __restrict__ Wot) {
    __shared__ short tile[32 * 33];
    const int bz = blockIdx.z;
    if (bz == 4) {
        const int n4 = MTOT * DIN / 4;
        int i = (blockIdx.y * 24 + blockIdx.x) * 256 + threadIdx.x;
        for (; i < n4; i += 24 * 24 * 256) {
            float4 v = ((const float4*)x)[i];
            short4 o;
            o.x = f2bf(v.x); o.y = f2bf(v.y); o.z = f2bf(v.z); o.w = f2bf(v.w);
            ((short4*)Xb)[i] = o;
        }
        return;
    }
    const int bx = blockIdx.x, by = blockIdx.y;
    const float* W = (bz == 0) ? Wq : (bz == 1) ? Wk : (bz == 2) ? Wv : Wo;
    const int tx = threadIdx.x & 31, ty = threadIdx.x >> 5;
    for (int i = 0; i < 4; i++) {
        int k = by * 32 + ty + i * 8;
        tile[(ty + i * 8) * 33 + tx] = f2bf(W[(size_t)k * DOUT + bx * 32 + tx]);
    }
    __syncthreads();
    for (int i = 0; i < 4; i++) {
        int n = bx * 32 + ty + i * 8;
        int k = by * 32 + tx;
        short v = tile[tx * 33 + ty + i * 8];
        if (bz < 3) Wqkvt[(size_t)(bz * DOUT + n) * DIN + k] = v;
        else        Wot[(size_t)n * DOUT + k] = v;
    }
}

// ---- QKV GEMM R15: BK=32, prefetch double-buffer (A0|B0|A1|B1 = 32 KB).
// Staging/read = R6-verified BK=32 pattern. One barrier per K-iter; loads for
// tile k+1 land during tile k's 16 MFMAs. ----
__global__ __launch_bounds__(256) void qkv_gemm_kernel(const short* __restrict__ Xb,
                                                       const short* __restrict__ Wt,
                                                       short* __restrict__ Qb,
                                                       short* __restrict__ Kb,
                                                       short* __restrict__ Vt) {
    __shared__ __align__(16) short lds[16384];   // A0:0 B0:4096 A1:8192 B1:12288
    const int t = threadIdx.x;
    const int w = t >> 6, lane = t & 63;
    const int quad = lane >> 4, l15 = lane & 15;
    const int m0 = blockIdx.x * 128, n0 = blockIdx.y * 128;
    const int wm = (w >> 1) * 64, wn = (w & 1) * 64;

    float4v acc[4][4];
    for (int i = 0; i < 4; i++)
        for (int j = 0; j < 4; j++)
            acc[i][j] = (float4v)0.0f;

    const int rA = t >> 2;
    const int cSw = ((t & 3) ^ ((t >> 3) & 3)) * 8;
    const short* gA0 = Xb + (size_t)(m0 + rA) * DIN + cSw;
    const short* gB0 = Wt + (size_t)(n0 + rA) * DIN + cSw;
    const int pos = (quad ^ ((l15 >> 1) & 3)) * 8;

    auto stage = [&](int buf, int k0) {
        int off = buf << 13;                  // 8192 shorts per buffer set
        gload_lds16(gA0 + k0,            &lds[off + t * 8]);
        gload_lds16(gA0 + 64 * DIN + k0, &lds[off + (t + 256) * 8]);
        gload_lds16(gB0 + k0,            &lds[off + 4096 + t * 8]);
        gload_lds16(gB0 + 64 * DIN + k0, &lds[off + 4096 + (t + 256) * 8]);
    };

    stage(0, 0);
    for (int it = 0; it < DIN / 32; ++it) {
        __syncthreads();
        if (it + 1 < DIN / 32) stage((it & 1) ^ 1, (it + 1) * 32);
        const short* A_ = lds + ((it & 1) << 13);
        const short* B_ = A_ + 4096;
        bf16x8 af[4], bfr[4];
        for (int i = 0; i < 4; i++) af[i]  = *(const bf16x8*)&A_[(wm + i * 16 + l15) * 32 + pos];
        for (int j = 0; j < 4; j++) bfr[j] = *(const bf16x8*)&B_[(wn + j * 16 + l15) * 32 + pos];
        for (int i = 0; i < 4; i++)
            for (int j = 0; j < 4; j++)
                acc[i][j] = __builtin_amdgcn_mfma_f32_16x16x32_bf16(af[i], bfr[j], acc[i][j], 0, 0, 0);
    }
    __syncthreads();   // protect epilogue's LDS reuse vs last-iter reads

    const int which = n0 / DOUT;
    if (which < 2) {
        // Q/K epilogue: single-pass 128x128 LDS tile, 1 barrier, b128 stores.
        short* ldsT = lds;   // 128 x 128 shorts = 32 KB
        const float sc = (which == 0) ? QSCALE : 1.0f;
        short* dst = (which == 0) ? Qb : Kb;
        const int n0sec = n0 - which * DOUT;
        for (int i = 0; i < 4; i++)
            for (int j = 0; j < 4; j++) {
                int col = wn + j * 16 + l15;
                int cx = col >> 3, co = col & 7;
                for (int r = 0; r < 4; r++) {
                    int row = wm + i * 16 + quad * 4 + r;
                    ldsT[row * 128 + ((cx ^ (row & 7)) * 8 + co)] = f2bf(acc[i][j][r] * sc);
                }
            }
        __syncthreads();
        for (int p = 0; p < 8; p++) {
            int row = p * 16 + (t >> 4);
            int cL = t & 15;
            short8v v = *(const short8v*)&ldsT[row * 128 + ((cL ^ (row & 7)) * 8)];
            int mg = m0 + row;
            int b2 = mg >> 11, tq = mg & 2047;
            int colg = n0sec + cL * 8;
            int hh = colg >> 6, d = colg & 63;
            *(short8v*)&dst[((size_t)((b2 * HH + hh) * TT + tq) << 6) + d] = v;
        }
    } else {
        // V epilogue: single-pass transpose 128(d) x 128(t) LDS tile, b128 stores.
        short* ldsT = lds;   // 128 x 128 shorts = 32 KB
        const int n0r = n0 - 2 * DOUT;
        const int b = m0 >> 11, tq0 = m0 & 2047;
        for (int i = 0; i < 4; i++)
            for (int j = 0; j < 4; j++)
                for (int r = 0; r < 4; r++) {
                    int nl = wn + j * 16 + l15;            // d-direction 0..127
                    int ml = wm + i * 16 + quad * 4 + r;   // t-direction 0..127
                    int c = ml >> 3, o = ml & 7;
                    ldsT[nl * 128 + ((c ^ (nl & 7)) * 8 + o)] = f2bf(acc[i][j][r]);
                }
        __syncthreads();
        for (int p = 0; p < 8; p++) {
            int nrow = p * 16 + (t >> 4);
            int cc = t & 15;
            short8v v = *(const short8v*)&ldsT[nrow * 128 + ((cc ^ (nrow & 7)) * 8)];
            int colg = n0r + nrow;
            int hh = colg >> 6, d = colg & 63;
            *(short8v*)&Vt[(size_t)((b * HH + hh) * HD + d) * TT + tq0 + cc * 8] = v;
        }
    }
}

// ---- Flash attention (R12/R9, banked 60.5us): kt-interleave + T5 setprio ----
__global__ __launch_bounds__(256, 3) void attn_kernel(const short* __restrict__ Qb,
                                                      const short* __restrict__ Kb,
                                                      const short* __restrict__ Vt,
                                                      short* __restrict__ Ctx) {
    __shared__ __align__(16) short ldsK[2][64 * 64];
    __shared__ __align__(16) short ldsV[2][64 * 64];
    const int t = threadIdx.x;
    const int w = t >> 6, lane = t & 63;
    const int half = lane >> 5, m = lane & 31;
    const int bh = blockIdx.x;
    const int b = bh / HH, h = bh - b * HH;
    const int q0 = blockIdx.y * 128 + w * 32;

    const short* Qbase = Qb + (size_t)bh * TT * HD;
    const short* Kbase = Kb + (size_t)bh * TT * HD;
    const short* Vbase = Vt + (size_t)bh * HD * TT;

    bf16x8 qf[4];
#pragma unroll
    for (int s = 0; s < 4; s++)
        qf[s] = *(const bf16x8*)&Qbase[(q0 + m) * HD + s * 16 + half * 8];

    int kOff[2], vOff[2];
    {
        int r5 = t >> 3;
        int pi = ((r5 >> 3) & 1) * 16 + ((r5 >> 2) & 1) * 8 + ((r5 >> 4) & 1) * 4 + (r5 & 3);
#pragma unroll
        for (int g = 0; g < 2; g++) {
            kOff[g] = (g * 32 + pi) * 64 + (((t & 7) ^ (r5 & 7)) * 8);
            int vrow = g * 32 + r5;
            vOff[g] = vrow * TT + (((t & 7) ^ (vrow & 7)) * 8);
        }
    }

    auto stage = [&](int buf, int u0) {
#pragma unroll
        for (int g = 0; g < 2; g++)
            gload_lds16(Kbase + (size_t)u0 * 64 + kOff[g], &ldsK[buf][(g * 256 + t) * 8]);
#pragma unroll
        for (int g = 0; g < 2; g++)
            gload_lds16(Vbase + (size_t)u0 + vOff[g], &ldsV[buf][(g * 256 + t) * 8]);
    };

    float16v accO[2];
    accO[0] = (float16v)0.0f;
    accO[1] = (float16v)0.0f;
    float lsum = 0.0f;

    stage(0, 0);

    for (int it = 0; it < TT / 64; ++it) {
        __syncthreads();
        const int buf = it & 1;
        if (it + 1 < TT / 64) stage(buf ^ 1, (it + 1) * 64);
        const short* K_ = &ldsK[buf][0];
        const short* V_ = &ldsV[buf][0];

        // ---- QK for both kt halves: two independent accumulation chains ----
        float16v st0 = (float16v)0.0f;
        float16v st1 = (float16v)0.0f;
        __builtin_amdgcn_s_setprio(1);
#pragma unroll
        for (int s = 0; s < 4; s++) {
            bf16x8 ka = *(const bf16x8*)&K_[m * 64 + (((s * 2 + half) ^ (m & 7)) * 8)];
            st0 = __builtin_amdgcn_mfma_f32_32x32x16_bf16(ka, qf[s], st0, 0, 0, 0);
        }
#pragma unroll
        for (int s = 0; s < 4; s++) {
            bf16x8 ka = *(const bf16x8*)&K_[(32 + m) * 64 + (((s * 2 + half) ^ (m & 7)) * 8)];
            st1 = __builtin_amdgcn_mfma_f32_32x32x16_bf16(ka, qf[s], st1, 0, 0, 0);
        }
        __builtin_amdgcn_s_setprio(0);

        // ---- kt=0: softmax (overlaps QK1 in-flight), PV, then tree-sum ----
        {
            float pe[16];
#pragma unroll
            for (int i = 0; i < 16; i++) pe[i] = __builtin_amdgcn_exp2f(st0[i]);
            bf16x8 ap[2];
#pragma unroll
            for (int i = 0; i < 4; i++) {
                ap[0][i]     = (__bf16)pe[i];
                ap[0][4 + i] = (__bf16)pe[8 + i];
                ap[1][i]     = (__bf16)pe[4 + i];
                ap[1][4 + i] = (__bf16)pe[12 + i];
            }
            __builtin_amdgcn_s_setprio(1);
#pragma unroll
            for (int ks = 0; ks < 2; ks++)
#pragma unroll
                for (int dt = 0; dt < 2; dt++) {
                    int row = dt * 32 + m;
                    bf16x8 bv = *(const bf16x8*)&V_[row * 64 + (((ks * 2 + half) ^ (row & 7)) * 8)];
                    accO[dt] = __builtin_amdgcn_mfma_f32_32x32x16_bf16(ap[ks], bv, accO[dt], 0, 0, 0);
                }
            __builtin_amdgcn_s_setprio(0);
            float ps[8];
#pragma unroll
            for (int i = 0; i < 8; i++) ps[i] = pe[i] + pe[i + 8];
#pragma unroll
            for (int i = 0; i < 4; i++) ps[i] += ps[i + 4];
            ps[0] += ps[2]; ps[1] += ps[3];
            lsum += ps[0] + ps[1];
        }

        // ---- kt=1: softmax (overlaps PV0 in-flight), PV, tree-sum ----
        {
            float pe[16];
#pragma unroll
            for (int i = 0; i < 16; i++) pe[i] = __builtin_amdgcn_exp2f(st1[i]);
            bf16x8 ap[2];
#pragma unroll
            for (int i = 0; i < 4; i++) {
                ap[0][i]     = (__bf16)pe[i];
                ap[0][4 + i] = (__bf16)pe[8 + i];
                ap[1][i]     = (__bf16)pe[4 + i];
                ap[1][4 + i] = (__bf16)pe[12 + i];
            }
            __builtin_amdgcn_s_setprio(1);
#pragma unroll
            for (int ks = 0; ks < 2; ks++)
#pragma unroll
                for (int dt = 0; dt < 2; dt++) {
                    int row = dt * 32 + m;
                    bf16x8 bv = *(const bf16x8*)&V_[row * 64 + (((4 + ks * 2 + half) ^ (row & 7)) * 8)];
                    accO[dt] = __builtin_amdgcn_mfma_f32_32x32x16_bf16(ap[ks], bv, accO[dt], 0, 0, 0);
                }
            __builtin_amdgcn_s_setprio(0);
            float ps[8];
#pragma unroll
            for (int i = 0; i < 8; i++) ps[i] = pe[i] + pe[i + 8];
#pragma unroll
            for (int i = 0; i < 4; i++) ps[i] += ps[i + 4];
            ps[0] += ps[2]; ps[1] += ps[3];
            lsum += ps[0] + ps[1];
        }
    }

    {
        float v = lsum + __shfl_xor(lsum, 32);
        float linv = 1.0f / v;
#pragma unroll
        for (int s = 0; s < 4; s++)
#pragma unroll
            for (int i = 0; i < 4; i++) {
                int reg = s * 4 + i;
                int qrow = i + s * 8 + half * 4;
                float ln = __shfl(linv, qrow);
                int qg = q0 + qrow;
                size_t base = (size_t)(b * TT + qg) * DOUT + h * HD + m;
                Ctx[base]      = f2bf(accO[0][reg] * ln);
                Ctx[base + 32] = f2bf(accO[1][reg] * ln);
            }
    }
}

// ---- Out GEMM R15: 64x128 tiles, BK=32 prefetch double-buffer (24 KB).
// A0:0 B0:2048 A1:6144 B1:8192 (shorts). Staging/read = R6-verified. ----
__global__ __launch_bounds__(256) void out_gemm_kernel(const short* __restrict__ Cb,
                                                       const short* __restrict__ Wot,
                                                       const float* __restrict__ bo,
                                                       float* __restrict__ out) {
    __shared__ __align__(16) short lds[12288];   // 24 KB
    const int t = threadIdx.x;
    const int w = t >> 6, lane = t & 63;
    const int quad = lane >> 4, l15 = lane & 15;
    const int m0 = blockIdx.x * 64, n0 = blockIdx.y * 128;
    const int wn = w * 32;

    float4v acc[4][2];
    for (int i = 0; i < 4; i++)
        for (int j = 0; j < 2; j++)
            acc[i][j] = (float4v)0.0f;

    const int rA = t >> 2;
    const int cSw = ((t & 3) ^ ((t >> 3) & 3)) * 8;
    const short* gA0 = Cb + (size_t)(m0 + rA) * DOUT + cSw;
    const short* gB0 = Wot + (size_t)(n0 + rA) * DOUT + cSw;
    const int pos = (quad ^ ((l15 >> 1) & 3)) * 8;

    auto stage = [&](int buf, int k0) {
        int off = buf * 6144;
        gload_lds16(gA0 + k0,             &lds[off + t * 8]);
        gload_lds16(gB0 + k0,             &lds[off + 2048 + t * 8]);
        gload_lds16(gB0 + 64 * DOUT + k0, &lds[off + 2048 + (t + 256) * 8]);
    };

    stage(0, 0);
    for (int it = 0; it < DOUT / 32; ++it) {
        __syncthreads();
        if (it + 1 < DOUT / 32) stage((it & 1) ^ 1, (it + 1) * 32);
        const short* A_ = lds + (it & 1) * 6144;
        const short* B_ = A_ + 2048;
        bf16x8 af[4], bfr[2];
        for (int i = 0; i < 4; i++) af[i]  = *(const bf16x8*)&A_[(i * 16 + l15) * 32 + pos];
        for (int j = 0; j < 2; j++) bfr[j] = *(const bf16x8*)&B_[(wn + j * 16 + l15) * 32 + pos];
        for (int i = 0; i < 4; i++)
            for (int j = 0; j < 2; j++)
                acc[i][j] = __builtin_amdgcn_mfma_f32_16x16x32_bf16(af[i], bfr[j], acc[i][j], 0, 0, 0);
    }

    for (int i = 0; i < 4; i++) {
        int m = m0 + i * 16 + quad * 4;
        for (int j = 0; j < 2; j++) {
            int n = n0 + wn + j * 16 + l15;
            float bias = bo[n];
            for (int r = 0; r < 4; r++)
                out[(size_t)(m + r) * DOUT + n] = acc[i][j][r] + bias;
        }
    }
}

extern "C" void kernel_launch(void* const* d_in, const int* in_sizes, int n_in,
                              void* d_out, int out_size, void* d_ws, size_t ws_size,
                              hipStream_t stream) {
    const float* x  = (const float*)d_in[0];
    const float* Wq = (const float*)d_in[1];
    const float* Wk = (const float*)d_in[2];
    const float* Wv = (const float*)d_in[3];
    const float* Wo = (const float*)d_in[4];
    const float* bo = (const float*)d_in[5];
    float* out = (float*)d_out;

    char* ws = (char*)d_ws;
    short* Xb    = (short*)(ws + 0);          // 12582912
    short* Wqkvt = (short*)(ws + 12582912);   //  3538944
    short* Wot   = (short*)(ws + 16121856);   //  1179648
    short* Qb    = (short*)(ws + 17301504);   // 12582912
    short* Kb    = (short*)(ws + 29884416);   // 12582912
    short* Vt    = (short*)(ws + 42467328);   // 12582912
    short* Cb    = (short*)(ws + 55050240);   // 12582912 -> total 67633152 B

    prep_kernel<<<dim3(24, 24, 5), 256, 0, stream>>>(x, Wq, Wk, Wv, Wo, Xb, Wqkvt, Wot);
    qkv_gemm_kernel<<<dim3(MTOT / 128, NQKV / 128), 256, 0, stream>>>(Xb, Wqkvt, Qb, Kb, Vt);
    attn_kernel<<<dim3(BB * HH, TT / 128), 256, 0, stream>>>(Qb, Kb, Vt, Cb);
    out_gemm_kernel<<<dim3(MTOT / 64, DOUT / 128), 256, 0, stream>>>(Cb, Wot, bo, out);
}

// Round 11
// 198.841 us; speedup vs baseline: 1.0970x; 1.0432x over previous
//
#include <hip/hip_runtime.h>
#include <hip/hip_bf16.h>
#include <stdint.h>

// MHA fwd, B=4 T=2048 D=768 H=12 HD=64, fp32 io, NO mask, scale=1/8.
// R16: R12 base (banked 204.3) + x-cast fused into qkv A-staging (reg-staged
// float4x2 -> cvt -> ds_write_b128, same LDS image; B stays global_load_lds).
// Deletes the cast pass (~24MB rd + 12MB wr). R15 dbuf was null (3rd
// structural null -- 2-barrier template self-hides staging latency per guide
// m99/m131). attn/out/prep-W byte-frozen from R12.

#define HH   12
#define TT   2048
#define DIN  768
#define DOUT 768
#define HD   64
#define BB   4
#define MTOT (BB*TT)      // 8192
#define NQKV (3*DOUT)     // 2304
#define QSCALE 0.1803368801111832f   // 0.125 * log2(e)

typedef float  float4v  __attribute__((ext_vector_type(4)));
typedef float  float16v __attribute__((ext_vector_type(16)));
typedef __bf16 bf16x8   __attribute__((ext_vector_type(8)));
typedef short  short8v  __attribute__((ext_vector_type(8)));

#define AS1 __attribute__((address_space(1)))
#define AS3 __attribute__((address_space(3)))

static __device__ __forceinline__ void gload_lds16(const void* g, void* l) {
    __builtin_amdgcn_global_load_lds((AS1 void*)g, (AS3 void*)l, 16, 0, 0);
}

static __device__ __forceinline__ short f2bf(float f) {
    __bf16 h = (__bf16)f;
    return __builtin_bit_cast(short, h);
}

// ---- Prep: weight transpose tiles only (x-cast now fused into qkv) ----
__global__ __launch_bounds__(256) void prep_kernel(const float* __restrict__ Wq,
                                                   const float* __restrict__ Wk,
                                                   const float* __restrict__ Wv,
                                                   const float* __restrict__ Wo,
                                                   short* __restrict__ Wqkvt,
                                                   short* __restrict__ Wot) {
    __shared__ short tile[32 * 33];
    const int bz = blockIdx.z;
    const int bx = blockIdx.x, by = blockIdx.y;
    const float* W = (bz == 0) ? Wq : (bz == 1) ? Wk : (bz == 2) ? Wv : Wo;
    const int tx = threadIdx.x & 31, ty = threadIdx.x >> 5;
    for (int i = 0; i < 4; i++) {
        int k = by * 32 + ty + i * 8;
        tile[(ty + i * 8) * 33 + tx] = f2bf(W[(size_t)k * DOUT + bx * 32 + tx]);
    }
    __syncthreads();
    for (int i = 0; i < 4; i++) {
        int n = bx * 32 + ty + i * 8;
        int k = by * 32 + tx;
        short v = tile[tx * 33 + ty + i * 8];
        if (bz < 3) Wqkvt[(size_t)(bz * DOUT + n) * DIN + k] = v;
        else        Wot[(size_t)n * DOUT + k] = v;
    }
}

// ---- QKV GEMM R16: C[8192][2304] = x(cast) @ Wqkvt^T, BK=64.
// A staged from fp32 x via reg-cast (float4 x2 -> cvt -> ds_write_b128),
// producing the EXACT LDS image of the R8/R12 gload path. B via gload_lds.
__global__ __launch_bounds__(256) void qkv_gemm_kernel(const float* __restrict__ x,
                                                       const short* __restrict__ Wt,
                                                       short* __restrict__ Qb,
                                                       short* __restrict__ Kb,
                                                       short* __restrict__ Vt) {
    __shared__ __align__(16) short lds[16384];   // GEMM: A|B 32KB; epilogue: 32KB tile
    short* ldsA = lds;           // 128 x 64
    short* ldsB = lds + 8192;    // 128 x 64
    const int t = threadIdx.x;
    const int w = t >> 6, lane = t & 63;
    const int quad = lane >> 4, l15 = lane & 15;
    const int m0 = blockIdx.x * 128, n0 = blockIdx.y * 128;
    const int wm = (w >> 1) * 64, wn = (w & 1) * 64;

    float4v acc[4][4];
    for (int i = 0; i < 4; i++)
        for (int j = 0; j < 4; j++)
            acc[i][j] = (float4v)0.0f;

    const int rA = t >> 3;                               // 0..31
    const int cS = ((t & 7) ^ ((t >> 3) & 7)) * 8;       // source col-granule * 8
    const float* xA0 = x + (size_t)(m0 + rA) * DIN + cS;
    const short* gB0 = Wt + (size_t)(n0 + rA) * DIN + cS;

    for (int k0 = 0; k0 < DIN; k0 += 64) {
        // B first: fire-and-forget DMA while A reg-stages.
#pragma unroll
        for (int g = 0; g < 4; g++)
            gload_lds16(gB0 + (size_t)g * 32 * DIN + k0, &ldsB[(g * 256 + t) * 8]);
#pragma unroll
        for (int g = 0; g < 4; g++) {
            const float* src = xA0 + (size_t)g * 32 * DIN + k0;
            float4 lo = *(const float4*)src;
            float4 hi = *(const float4*)(src + 4);
            short8v s;
            s[0] = f2bf(lo.x); s[1] = f2bf(lo.y); s[2] = f2bf(lo.z); s[3] = f2bf(lo.w);
            s[4] = f2bf(hi.x); s[5] = f2bf(hi.y); s[6] = f2bf(hi.z); s[7] = f2bf(hi.w);
            *(short8v*)&ldsA[(g * 256 + t) * 8] = s;
        }
        __syncthreads();
#pragma unroll
        for (int kk = 0; kk < 2; kk++) {
            bf16x8 af[4], bfr[4];
            const int pos = ((kk * 4 + quad) ^ (l15 & 7)) * 8;
            for (int i = 0; i < 4; i++) af[i]  = *(const bf16x8*)&ldsA[(wm + i * 16 + l15) * 64 + pos];
            for (int j = 0; j < 4; j++) bfr[j] = *(const bf16x8*)&ldsB[(wn + j * 16 + l15) * 64 + pos];
            for (int i = 0; i < 4; i++)
                for (int j = 0; j < 4; j++)
                    acc[i][j] = __builtin_amdgcn_mfma_f32_16x16x32_bf16(af[i], bfr[j], acc[i][j], 0, 0, 0);
        }
        __syncthreads();
    }

    const int which = n0 / DOUT;
    if (which < 2) {
        // Q/K epilogue: single-pass 128x128 LDS tile, 1 barrier, b128 stores.
        short* ldsT = lds;   // 128 x 128 shorts = 32 KB
        const float sc = (which == 0) ? QSCALE : 1.0f;
        short* dst = (which == 0) ? Qb : Kb;
        const int n0sec = n0 - which * DOUT;
        for (int i = 0; i < 4; i++)
            for (int j = 0; j < 4; j++) {
                int col = wn + j * 16 + l15;
                int cx = col >> 3, co = col & 7;
                for (int r = 0; r < 4; r++) {
                    int row = wm + i * 16 + quad * 4 + r;
                    ldsT[row * 128 + ((cx ^ (row & 7)) * 8 + co)] = f2bf(acc[i][j][r] * sc);
                }
            }
        __syncthreads();
        for (int p = 0; p < 8; p++) {
            int row = p * 16 + (t >> 4);
            int cL = t & 15;
            short8v v = *(const short8v*)&ldsT[row * 128 + ((cL ^ (row & 7)) * 8)];
            int mg = m0 + row;
            int b2 = mg >> 11, tq = mg & 2047;
            int colg = n0sec + cL * 8;
            int hh = colg >> 6, d = colg & 63;
            *(short8v*)&dst[((size_t)((b2 * HH + hh) * TT + tq) << 6) + d] = v;
        }
    } else {
        // V epilogue: single-pass transpose 128(d) x 128(t) LDS tile, b128 stores.
        short* ldsT = lds;   // 128 x 128 shorts = 32 KB
        const int n0r = n0 - 2 * DOUT;
        const int b = m0 >> 11, tq0 = m0 & 2047;
        for (int i = 0; i < 4; i++)
            for (int j = 0; j < 4; j++)
                for (int r = 0; r < 4; r++) {
                    int nl = wn + j * 16 + l15;            // d-direction 0..127
                    int ml = wm + i * 16 + quad * 4 + r;   // t-direction 0..127
                    int c = ml >> 3, o = ml & 7;
                    ldsT[nl * 128 + ((c ^ (nl & 7)) * 8 + o)] = f2bf(acc[i][j][r]);
                }
        __syncthreads();
        for (int p = 0; p < 8; p++) {
            int nrow = p * 16 + (t >> 4);
            int cc = t & 15;
            short8v v = *(const short8v*)&ldsT[nrow * 128 + ((cc ^ (nrow & 7)) * 8)];
            int colg = n0r + nrow;
            int hh = colg >> 6, d = colg & 63;
            *(short8v*)&Vt[(size_t)((b * HH + hh) * HD + d) * TT + tq0 + cc * 8] = v;
        }
    }
}

// ---- Flash attention (R12/R9, banked): kt-interleave + T5 setprio ----
__global__ __launch_bounds__(256, 3) void attn_kernel(const short* __restrict__ Qb,
                                                      const short* __restrict__ Kb,
                                                      const short* __restrict__ Vt,
                                                      short* __restrict__ Ctx) {
    __shared__ __align__(16) short ldsK[2][64 * 64];
    __shared__ __align__(16) short ldsV[2][64 * 64];
    const int t = threadIdx.x;
    const int w = t >> 6, lane = t & 63;
    const int half = lane >> 5, m = lane & 31;
    const int bh = blockIdx.x;
    const int b = bh / HH, h = bh - b * HH;
    const int q0 = blockIdx.y * 128 + w * 32;

    const short* Qbase = Qb + (size_t)bh * TT * HD;
    const short* Kbase = Kb + (size_t)bh * TT * HD;
    const short* Vbase = Vt + (size_t)bh * HD * TT;

    bf16x8 qf[4];
#pragma unroll
    for (int s = 0; s < 4; s++)
        qf[s] = *(const bf16x8*)&Qbase[(q0 + m) * HD + s * 16 + half * 8];

    int kOff[2], vOff[2];
    {
        int r5 = t >> 3;
        int pi = ((r5 >> 3) & 1) * 16 + ((r5 >> 2) & 1) * 8 + ((r5 >> 4) & 1) * 4 + (r5 & 3);
#pragma unroll
        for (int g = 0; g < 2; g++) {
            kOff[g] = (g * 32 + pi) * 64 + (((t & 7) ^ (r5 & 7)) * 8);
            int vrow = g * 32 + r5;
            vOff[g] = vrow * TT + (((t & 7) ^ (vrow & 7)) * 8);
        }
    }

    auto stage = [&](int buf, int u0) {
#pragma unroll
        for (int g = 0; g < 2; g++)
            gload_lds16(Kbase + (size_t)u0 * 64 + kOff[g], &ldsK[buf][(g * 256 + t) * 8]);
#pragma unroll
        for (int g = 0; g < 2; g++)
            gload_lds16(Vbase + (size_t)u0 + vOff[g], &ldsV[buf][(g * 256 + t) * 8]);
    };

    float16v accO[2];
    accO[0] = (float16v)0.0f;
    accO[1] = (float16v)0.0f;
    float lsum = 0.0f;

    stage(0, 0);

    for (int it = 0; it < TT / 64; ++it) {
        __syncthreads();
        const int buf = it & 1;
        if (it + 1 < TT / 64) stage(buf ^ 1, (it + 1) * 64);
        const short* K_ = &ldsK[buf][0];
        const short* V_ = &ldsV[buf][0];

        // ---- QK for both kt halves: two independent accumulation chains ----
        float16v st0 = (float16v)0.0f;
        float16v st1 = (float16v)0.0f;
        __builtin_amdgcn_s_setprio(1);
#pragma unroll
        for (int s = 0; s < 4; s++) {
            bf16x8 ka = *(const bf16x8*)&K_[m * 64 + (((s * 2 + half) ^ (m & 7)) * 8)];
            st0 = __builtin_amdgcn_mfma_f32_32x32x16_bf16(ka, qf[s], st0, 0, 0, 0);
        }
#pragma unroll
        for (int s = 0; s < 4; s++) {
            bf16x8 ka = *(const bf16x8*)&K_[(32 + m) * 64 + (((s * 2 + half) ^ (m & 7)) * 8)];
            st1 = __builtin_amdgcn_mfma_f32_32x32x16_bf16(ka, qf[s], st1, 0, 0, 0);
        }
        __builtin_amdgcn_s_setprio(0);

        // ---- kt=0: softmax (overlaps QK1 in-flight), PV, then tree-sum ----
        {
            float pe[16];
#pragma unroll
            for (int i = 0; i < 16; i++) pe[i] = __builtin_amdgcn_exp2f(st0[i]);
            bf16x8 ap[2];
#pragma unroll
            for (int i = 0; i < 4; i++) {
                ap[0][i]     = (__bf16)pe[i];
                ap[0][4 + i] = (__bf16)pe[8 + i];
                ap[1][i]     = (__bf16)pe[4 + i];
                ap[1][4 + i] = (__bf16)pe[12 + i];
            }
            __builtin_amdgcn_s_setprio(1);
#pragma unroll
            for (int ks = 0; ks < 2; ks++)
#pragma unroll
                for (int dt = 0; dt < 2; dt++) {
                    int row = dt * 32 + m;
                    bf16x8 bv = *(const bf16x8*)&V_[row * 64 + (((ks * 2 + half) ^ (row & 7)) * 8)];
                    accO[dt] = __builtin_amdgcn_mfma_f32_32x32x16_bf16(ap[ks], bv, accO[dt], 0, 0, 0);
                }
            __builtin_amdgcn_s_setprio(0);
            float ps[8];
#pragma unroll
            for (int i = 0; i < 8; i++) ps[i] = pe[i] + pe[i + 8];
#pragma unroll
            for (int i = 0; i < 4; i++) ps[i] += ps[i + 4];
            ps[0] += ps[2]; ps[1] += ps[3];
            lsum += ps[0] + ps[1];
        }

        // ---- kt=1: softmax (overlaps PV0 in-flight), PV, tree-sum ----
        {
            float pe[16];
#pragma unroll
            for (int i = 0; i < 16; i++) pe[i] = __builtin_amdgcn_exp2f(st1[i]);
            bf16x8 ap[2];
#pragma unroll
            for (int i = 0; i < 4; i++) {
                ap[0][i]     = (__bf16)pe[i];
                ap[0][4 + i] = (__bf16)pe[8 + i];
                ap[1][i]     = (__bf16)pe[4 + i];
                ap[1][4 + i] = (__bf16)pe[12 + i];
            }
            __builtin_amdgcn_s_setprio(1);
#pragma unroll
            for (int ks = 0; ks < 2; ks++)
#pragma unroll
                for (int dt = 0; dt < 2; dt++) {
                    int row = dt * 32 + m;
                    bf16x8 bv = *(const bf16x8*)&V_[row * 64 + (((4 + ks * 2 + half) ^ (row & 7)) * 8)];
                    accO[dt] = __builtin_amdgcn_mfma_f32_32x32x16_bf16(ap[ks], bv, accO[dt], 0, 0, 0);
                }
            __builtin_amdgcn_s_setprio(0);
            float ps[8];
#pragma unroll
            for (int i = 0; i < 8; i++) ps[i] = pe[i] + pe[i + 8];
#pragma unroll
            for (int i = 0; i < 4; i++) ps[i] += ps[i + 4];
            ps[0] += ps[2]; ps[1] += ps[3];
            lsum += ps[0] + ps[1];
        }
    }

    {
        float v = lsum + __shfl_xor(lsum, 32);
        float linv = 1.0f / v;
#pragma unroll
        for (int s = 0; s < 4; s++)
#pragma unroll
            for (int i = 0; i < 4; i++) {
                int reg = s * 4 + i;
                int qrow = i + s * 8 + half * 4;
                float ln = __shfl(linv, qrow);
                int qg = q0 + qrow;
                size_t base = (size_t)(b * TT + qg) * DOUT + h * HD + m;
                Ctx[base]      = f2bf(accO[0][reg] * ln);
                Ctx[base + 32] = f2bf(accO[1][reg] * ln);
            }
    }
}

// ---- Out GEMM (R12): 64x128 tiles, BK=64, grid 128x6 = 768 blocks = 3/CU ----
__global__ __launch_bounds__(256) void out_gemm_kernel(const short* __restrict__ Cb,
                                                       const short* __restrict__ Wot,
                                                       const float* __restrict__ bo,
                                                       float* __restrict__ out) {
    __shared__ __align__(16) short ldsA[64 * 64];    //  8 KB
    __shared__ __align__(16) short ldsB[128 * 64];   // 16 KB
    const int t = threadIdx.x;
    const int w = t >> 6, lane = t & 63;
    const int quad = lane >> 4, l15 = lane & 15;
    const int m0 = blockIdx.x * 64, n0 = blockIdx.y * 128;
    const int wn = w * 32;

    float4v acc[4][2];
    for (int i = 0; i < 4; i++)
        for (int j = 0; j < 2; j++)
            acc[i][j] = (float4v)0.0f;

    const int rA = t >> 3;                               // 0..31
    const int cS = ((t & 7) ^ ((t >> 3) & 7)) * 8;       // source col-granule * 8
    const short* gA0 = Cb + (size_t)(m0 + rA) * DOUT + cS;
    const short* gB0 = Wot + (size_t)(n0 + rA) * DOUT + cS;

    for (int k0 = 0; k0 < DOUT; k0 += 64) {
#pragma unroll
        for (int g = 0; g < 2; g++)
            gload_lds16(gA0 + (size_t)g * 32 * DOUT + k0, &ldsA[(g * 256 + t) * 8]);
#pragma unroll
        for (int g = 0; g < 4; g++)
            gload_lds16(gB0 + (size_t)g * 32 * DOUT + k0, &ldsB[(g * 256 + t) * 8]);
        __syncthreads();
#pragma unroll
        for (int kk = 0; kk < 2; kk++) {
            bf16x8 af[4], bfr[2];
            const int pos = ((kk * 4 + quad) ^ (l15 & 7)) * 8;
            for (int i = 0; i < 4; i++) af[i]  = *(const bf16x8*)&ldsA[(i * 16 + l15) * 64 + pos];
            for (int j = 0; j < 2; j++) bfr[j] = *(const bf16x8*)&ldsB[(wn + j * 16 + l15) * 64 + pos];
            for (int i = 0; i < 4; i++)
                for (int j = 0; j < 2; j++)
                    acc[i][j] = __builtin_amdgcn_mfma_f32_16x16x32_bf16(af[i], bfr[j], acc[i][j], 0, 0, 0);
        }
        __syncthreads();
    }

    for (int i = 0; i < 4; i++) {
        int m = m0 + i * 16 + quad * 4;
        for (int j = 0; j < 2; j++) {
            int n = n0 + wn + j * 16 + l15;
            float bias = bo[n];
            for (int r = 0; r < 4; r++)
                out[(size_t)(m + r) * DOUT + n] = acc[i][j][r] + bias;
        }
    }
}

extern "C" void kernel_launch(void* const* d_in, const int* in_sizes, int n_in,
                              void* d_out, int out_size, void* d_ws, size_t ws_size,
                              hipStream_t stream) {
    const float* x  = (const float*)d_in[0];
    const float* Wq = (const float*)d_in[1];
    const float* Wk = (const float*)d_in[2];
    const float* Wv = (const float*)d_in[3];
    const float* Wo = (const float*)d_in[4];
    const float* bo = (const float*)d_in[5];
    float* out = (float*)d_out;

    char* ws = (char*)d_ws;
    short* Wqkvt = (short*)(ws + 12582912);   //  3538944
    short* Wot   = (short*)(ws + 16121856);   //  1179648
    short* Qb    = (short*)(ws + 17301504);   // 12582912
    short* Kb    = (short*)(ws + 29884416);   // 12582912
    short* Vt    = (short*)(ws + 42467328);   // 12582912
    short* Cb    = (short*)(ws + 55050240);   // 12582912 -> total 67633152 B

    prep_kernel<<<dim3(24, 24, 4), 256, 0, stream>>>(Wq, Wk, Wv, Wo, Wqkvt, Wot);
    qkv_gemm_kernel<<<dim3(MTOT / 128, NQKV / 128), 256, 0, stream>>>(x, Wqkvt, Qb, Kb, Vt);
    attn_kernel<<<dim3(BB * HH, TT / 128), 256, 0, stream>>>(Qb, Kb, Vt, Cb);
    out_gemm_kernel<<<dim3(MTOT / 64, DOUT / 128), 256, 0, stream>>>(Cb, Wot, bo, out);
}